// Round 1
// baseline (544.054 us; speedup 1.0000x reference)
//
#include <hip/hip_runtime.h>

#define N_NODES 50000
#define N_EDGES 800000
#define F 64   // IN_FEATS == HIDDEN
#define C 32   // NUM_CLASSES

// ---------------- degree count: one thread per edge ----------------
__global__ void deg_kernel(const int* __restrict__ src, const int* __restrict__ dst,
                           float* __restrict__ deg_out, float* __restrict__ deg_in) {
    int e = blockIdx.x * blockDim.x + threadIdx.x;
    if (e < N_EDGES) {
        atomicAdd(&deg_out[src[e]], 1.0f);
        atomicAdd(&deg_in[dst[e]], 1.0f);
    }
}

// deg -> rsqrt(max(deg,1)) in place, over 2N contiguous floats (both arrays)
__global__ void norm_kernel(float* __restrict__ deg, int n) {
    int i = blockIdx.x * blockDim.x + threadIdx.x;
    if (i < n) deg[i] = rsqrtf(fmaxf(deg[i], 1.0f));
}

// ---------------- edge scatter: one wave per edge, lane = feature ----------------
// agg[dst[e]][l] += x[src[e]][l] * norm_src[src[e]]
__global__ void scatter_kernel(const float* __restrict__ x,
                               const float* __restrict__ norm_src,
                               const int* __restrict__ src,
                               const int* __restrict__ dst,
                               float* __restrict__ agg) {
    int gid  = blockIdx.x * blockDim.x + threadIdx.x;
    int e    = gid >> 6;          // wave id == edge id
    int lane = threadIdx.x & 63;  // feature
    if (e < N_EDGES) {
        int s = src[e];
        int d = dst[e];
        float v = x[(size_t)s * F + lane] * norm_src[s];
        atomicAdd(&agg[(size_t)d * F + lane], v);
    }
}

// ---------------- layer-1 GEMM: out = relu((agg*norm_dst) @ W + b), F->F ----------------
// block 256 = 4 nodes x 64 output features
__global__ void gemm1_relu_kernel(const float* __restrict__ agg,
                                  const float* __restrict__ norm_dst,
                                  const float* __restrict__ W,   // [F][F]
                                  const float* __restrict__ b,   // [F]
                                  float* __restrict__ out) {     // [N][F]
    __shared__ float sW[F * F];      // 16 KB
    __shared__ float srow[4][F];     // 1 KB
    int t = threadIdx.x;
    for (int i = t; i < F * F; i += 256) sW[i] = W[i];
    int local = t >> 6;      // 0..3
    int j     = t & 63;      // output feature
    int node  = blockIdx.x * 4 + local;
    float nd = 0.0f;
    if (node < N_NODES) {
        srow[local][j] = agg[(size_t)node * F + j];
        nd = norm_dst[node];
    }
    __syncthreads();
    if (node < N_NODES) {
        float acc = 0.0f;
#pragma unroll
        for (int i = 0; i < F; i++) acc += srow[local][i] * sW[i * F + j];
        out[(size_t)node * F + j] = fmaxf(acc * nd + b[j], 0.0f);
    }
}

// ---------------- layer-2 GEMM: out = (agg*norm_dst) @ W + b, F->C ----------------
// block 256 = 8 nodes x 32 output features
__global__ void gemm2_kernel(const float* __restrict__ agg,
                             const float* __restrict__ norm_dst,
                             const float* __restrict__ W,   // [F][C]
                             const float* __restrict__ b,   // [C]
                             float* __restrict__ out) {     // [N][C]
    __shared__ float sW[F * C];      // 8 KB
    __shared__ float srow[8][F];     // 2 KB
    int t = threadIdx.x;
    for (int i = t; i < F * C; i += 256) sW[i] = W[i];
    int local = t >> 5;      // 0..7
    int j     = t & 31;      // output class
    int node  = blockIdx.x * 8 + local;
    float nd = 0.0f;
    if (node < N_NODES) {
        srow[local][j]      = agg[(size_t)node * F + j];
        srow[local][j + 32] = agg[(size_t)node * F + j + 32];
        nd = norm_dst[node];
    }
    __syncthreads();
    if (node < N_NODES) {
        float acc = 0.0f;
#pragma unroll
        for (int i = 0; i < F; i++) acc += srow[local][i] * sW[i * C + j];
        out[(size_t)node * C + j] = acc * nd + b[j];
    }
}

extern "C" void kernel_launch(void* const* d_in, const int* in_sizes, int n_in,
                              void* d_out, int out_size, void* d_ws, size_t ws_size,
                              hipStream_t stream) {
    const float* features = (const float*)d_in[0];   // [N, 64]
    const int*   src      = (const int*)d_in[1];     // [E]
    const int*   dst      = (const int*)d_in[2];     // [E]
    const float* W1       = (const float*)d_in[3];   // [64,64]
    const float* b1       = (const float*)d_in[4];   // [64]
    const float* W2       = (const float*)d_in[5];   // [64,32]
    const float* b2       = (const float*)d_in[6];   // [32]
    float* out = (float*)d_out;                      // [N, 32]

    // workspace layout (floats):
    //   [0, 2N)                : deg_out | deg_in  -> becomes norm_src | norm_dst
    //   [2N, 2N+N*F)           : agg buffer (reused for both layers)
    //   [2N+N*F, 2N+2*N*F)     : h1 (layer-1 output)
    float* ws       = (float*)d_ws;
    float* deg      = ws;                 // 2N
    float* norm_src = ws;                 // N (after norm_kernel)
    float* norm_dst = ws + N_NODES;       // N
    float* agg      = ws + 2 * N_NODES;            // N*F
    float* h1       = agg + (size_t)N_NODES * F;   // N*F

    // 1) degrees
    hipMemsetAsync(deg, 0, 2 * N_NODES * sizeof(float), stream);
    deg_kernel<<<(N_EDGES + 255) / 256, 256, 0, stream>>>(src, dst, deg, deg + N_NODES);
    norm_kernel<<<(2 * N_NODES + 255) / 256, 256, 0, stream>>>(deg, 2 * N_NODES);

    // 2) layer 1: scatter + gemm(+relu)
    hipMemsetAsync(agg, 0, (size_t)N_NODES * F * sizeof(float), stream);
    scatter_kernel<<<(N_EDGES * 64) / 256, 256, 0, stream>>>(features, norm_src, src, dst, agg);
    gemm1_relu_kernel<<<(N_NODES + 3) / 4, 256, 0, stream>>>(agg, norm_dst, W1, b1, h1);

    // 3) layer 2: scatter + gemm
    hipMemsetAsync(agg, 0, (size_t)N_NODES * F * sizeof(float), stream);
    scatter_kernel<<<(N_EDGES * 64) / 256, 256, 0, stream>>>(h1, norm_src, src, dst, agg);
    gemm2_kernel<<<(N_NODES + 7) / 8, 256, 0, stream>>>(agg, norm_dst, W2, b2, out);
}

// Round 2
// 395.338 us; speedup vs baseline: 1.3762x; 1.3762x over previous
//
#include <hip/hip_runtime.h>

#define N_NODES 50000
#define N_EDGES 800000
#define F 64   // IN_FEATS == HIDDEN
#define C 32   // NUM_CLASSES

// ---------------- degree count: one thread per edge ----------------
__global__ void deg_kernel(const int* __restrict__ src, const int* __restrict__ dst,
                           float* __restrict__ out_deg, int* __restrict__ in_cnt) {
    int e = blockIdx.x * blockDim.x + threadIdx.x;
    if (e < N_EDGES) {
        atomicAdd(&out_deg[src[e]], 1.0f);
        atomicAdd(&in_cnt[dst[e]], 1);
    }
}

// norm_src = rsqrt(max(out_deg,1)) in place; norm_dst = rsqrt(max(in_cnt,1))
__global__ void norm_kernel(float* __restrict__ out_deg, const int* __restrict__ in_cnt,
                            float* __restrict__ norm_dst) {
    int i = blockIdx.x * blockDim.x + threadIdx.x;
    if (i < N_NODES) {
        out_deg[i] = rsqrtf(fmaxf(out_deg[i], 1.0f));
        norm_dst[i] = rsqrtf(fmaxf((float)in_cnt[i], 1.0f));
    }
}

// ---------------- exclusive prefix sum of in_cnt -> row_start, cursor ----------------
// single block of 1024 threads; cursor may alias cnt (each thread reads cnt[i]
// before writing cursor[i], same index only).
__global__ void scan_kernel(const int* __restrict__ cnt, int* __restrict__ row_start,
                            int* __restrict__ cursor) {
    __shared__ int wsum[16];
    __shared__ int woff[16];
    __shared__ int carry_s;
    int t = threadIdx.x;        // 0..1023
    int lane = t & 63;
    int w = t >> 6;             // wave 0..15
    if (t == 0) carry_s = 0;
    __syncthreads();
    for (int base = 0; base < N_NODES; base += 1024) {
        int i = base + t;
        int v = (i < N_NODES) ? cnt[i] : 0;
        int incl = v;
#pragma unroll
        for (int off = 1; off < 64; off <<= 1) {
            int u = __shfl_up(incl, off);
            if (lane >= off) incl += u;
        }
        if (lane == 63) wsum[w] = incl;
        __syncthreads();
        if (t < 16) {
            int s = wsum[t];
            int is = s;
#pragma unroll
            for (int off = 1; off < 16; off <<= 1) {
                int u = __shfl_up(is, off);
                if (t >= off) is += u;
            }
            woff[t] = is - s;   // exclusive wave offset
        }
        __syncthreads();
        int excl = carry_s + woff[w] + (incl - v);
        if (i < N_NODES) { row_start[i] = excl; cursor[i] = excl; }
        __syncthreads();
        if (t == 0) carry_s += woff[15] + wsum[15];
        __syncthreads();
    }
    if (t == 0) row_start[N_NODES] = carry_s;   // == N_EDGES
}

// ---------------- CSR build: atomic-ticket placement ----------------
__global__ void csr_kernel(const int* __restrict__ src, const int* __restrict__ dst,
                           int* __restrict__ cursor, int* __restrict__ csr) {
    int e = blockIdx.x * blockDim.x + threadIdx.x;
    if (e < N_EDGES) {
        int pos = atomicAdd(&cursor[dst[e]], 1);
        csr[pos] = src[e];
    }
}

// ---------------- y = (x @ W1) * norm_src  [N x 64] ----------------
// block 256 = 4 nodes x 64 output features
__global__ void gemm_y_kernel(const float* __restrict__ x,
                              const float* __restrict__ norm_src,
                              const float* __restrict__ W,   // [F][F]
                              float* __restrict__ y) {
    __shared__ float sW[F * F];      // 16 KB
    __shared__ float srow[4][F];
    int t = threadIdx.x;
    for (int i = t; i < F * F; i += 256) sW[i] = W[i];
    int local = t >> 6;
    int j     = t & 63;
    int node  = blockIdx.x * 4 + local;
    float ns = 0.0f;
    if (node < N_NODES) {
        srow[local][j] = x[(size_t)node * F + j];
        ns = norm_src[node];
    }
    __syncthreads();
    if (node < N_NODES) {
        float acc = 0.0f;
#pragma unroll
        for (int i = 0; i < F; i++) acc += srow[local][i] * sW[i * F + j];
        y[(size_t)node * F + j] = acc * ns;
    }
}

// ---------------- gather64: agg[n][l] = sum over in-edges of y[src][l] ----------------
// one wave per node, lane = feature
__global__ void gather64_kernel(const float* __restrict__ y,
                                const int* __restrict__ csr,
                                const int* __restrict__ row_start,
                                float* __restrict__ agg) {
    int gid  = blockIdx.x * blockDim.x + threadIdx.x;
    int node = gid >> 6;
    int lane = threadIdx.x & 63;
    if (node >= N_NODES) return;
    int s0 = row_start[node], s1 = row_start[node + 1];
    float acc = 0.0f;
    int e = s0;
    for (; e + 1 < s1; e += 2) {
        int sa = csr[e], sb = csr[e + 1];
        float va = y[(size_t)sa * F + lane];
        float vb = y[(size_t)sb * F + lane];
        acc += va;
        acc += vb;
    }
    if (e < s1) acc += y[(size_t)csr[e] * F + lane];
    agg[(size_t)node * F + lane] = acc;
}

// ---------------- h1 = relu(agg * norm_dst + b1), in place ----------------
__global__ void relu_nd_kernel(float* __restrict__ agg,
                               const float* __restrict__ norm_dst,
                               const float* __restrict__ b1) {
    int i = blockIdx.x * blockDim.x + threadIdx.x;
    if (i < N_NODES * F) {
        int node = i >> 6;
        int j = i & 63;
        agg[i] = fmaxf(agg[i] * norm_dst[node] + b1[j], 0.0f);
    }
}

// ---------------- g = (h1 @ W2) * norm_src  [N x 32] ----------------
// block 256 = 8 nodes x 32 outputs
__global__ void gemm_g_kernel(const float* __restrict__ h1,
                              const float* __restrict__ norm_src,
                              const float* __restrict__ W,   // [F][C]
                              float* __restrict__ g) {
    __shared__ float sW[F * C];      // 8 KB
    __shared__ float srow[8][F];
    int t = threadIdx.x;
    for (int i = t; i < F * C; i += 256) sW[i] = W[i];
    int local = t >> 5;
    int j     = t & 31;
    int node  = blockIdx.x * 8 + local;
    float ns = 0.0f;
    if (node < N_NODES) {
        srow[local][j]      = h1[(size_t)node * F + j];
        srow[local][j + 32] = h1[(size_t)node * F + j + 32];
        ns = norm_src[node];
    }
    __syncthreads();
    if (node < N_NODES) {
        float acc = 0.0f;
#pragma unroll
        for (int i = 0; i < F; i++) acc += srow[local][i] * sW[i * C + j];
        g[(size_t)node * C + j] = acc * ns;
    }
}

// ---------------- gather32 + epilogue: out = (sum g[src]) * norm_dst + b2 ----------------
// one wave per node; lanes split into 2 halves over edges, 32 feats each
__global__ void gather32_kernel(const float* __restrict__ g,
                                const int* __restrict__ csr,
                                const int* __restrict__ row_start,
                                const float* __restrict__ norm_dst,
                                const float* __restrict__ b2,
                                float* __restrict__ out) {
    int gid  = blockIdx.x * blockDim.x + threadIdx.x;
    int node = gid >> 6;
    if (node >= N_NODES) return;
    int lane = threadIdx.x & 63;
    int feat = lane & 31;
    int half = lane >> 5;
    int s0 = row_start[node], s1 = row_start[node + 1];
    float acc = 0.0f;
    for (int e = s0 + half; e < s1; e += 2) {
        acc += g[(size_t)csr[e] * C + feat];
    }
    acc += __shfl_down(acc, 32);   // fold half 1 into half 0
    if (half == 0) out[(size_t)node * C + feat] = acc * norm_dst[node] + b2[feat];
}

extern "C" void kernel_launch(void* const* d_in, const int* in_sizes, int n_in,
                              void* d_out, int out_size, void* d_ws, size_t ws_size,
                              hipStream_t stream) {
    const float* features = (const float*)d_in[0];   // [N, 64]
    const int*   src      = (const int*)d_in[1];     // [E]
    const int*   dst      = (const int*)d_in[2];     // [E]
    const float* W1       = (const float*)d_in[3];   // [64,64]
    const float* b1       = (const float*)d_in[4];   // [64]
    const float* W2       = (const float*)d_in[5];   // [64,32]
    const float* b2       = (const float*)d_in[6];   // [32]
    float* out = (float*)d_out;                      // [N, 32]

    // workspace layout (4-byte elements):
    //   [0,N)        out_deg -> norm_src (in place)
    //   [N,2N)       in_cnt (int) -> cursor (aliased, destroyed by csr build)
    //   [2N,3N)      norm_dst
    //   [3N,4N+1)    row_start
    //   [4N+1,...)   csr (E ints)
    //   then         y  [N*F]  (reused as g [N*C])
    //   then         agg[N*F]  (relu'd in place -> h1)
    float* ws_f     = (float*)d_ws;
    float* out_deg  = ws_f;                      // N floats (-> norm_src)
    float* norm_src = ws_f;
    int*   in_cnt   = (int*)(ws_f + N_NODES);    // N ints (-> cursor)
    int*   cursor   = in_cnt;
    float* norm_dst = ws_f + 2 * N_NODES;        // N floats
    int*   row_start= (int*)(ws_f + 3 * N_NODES);// N+1 ints
    int*   csr      = row_start + N_NODES + 1;   // E ints
    float* y        = (float*)(csr + N_EDGES);   // N*F floats (later aliased as g)
    float* agg      = y + (size_t)N_NODES * F;   // N*F floats (-> h1 in place)
    float* g        = y;

    // 1) degrees (zero the two count arrays: contiguous 2N elements)
    hipMemsetAsync(out_deg, 0, 2 * N_NODES * sizeof(float), stream);
    deg_kernel<<<(N_EDGES + 255) / 256, 256, 0, stream>>>(src, dst, out_deg, in_cnt);
    norm_kernel<<<(N_NODES + 255) / 256, 256, 0, stream>>>(out_deg, in_cnt, norm_dst);

    // 2) CSR by dst
    scan_kernel<<<1, 1024, 0, stream>>>(in_cnt, row_start, cursor);
    csr_kernel<<<(N_EDGES + 255) / 256, 256, 0, stream>>>(src, dst, cursor, csr);

    // 3) layer 1: y = (x@W1)*ns ; agg = gather(y) ; h1 = relu(agg*nd + b1)
    gemm_y_kernel<<<N_NODES / 4, 256, 0, stream>>>(features, norm_src, W1, y);
    gather64_kernel<<<N_NODES * 64 / 256, 256, 0, stream>>>(y, csr, row_start, agg);
    relu_nd_kernel<<<N_NODES * F / 256, 256, 0, stream>>>(agg, norm_dst, b1);

    // 4) layer 2: g = (h1@W2)*ns ; out = gather(g)*nd + b2
    gemm_g_kernel<<<N_NODES / 8, 256, 0, stream>>>(agg, norm_src, W2, g);
    gather32_kernel<<<N_NODES * 64 / 256, 256, 0, stream>>>(g, csr, row_start, norm_dst, b2, out);
}

// Round 4
// 338.289 us; speedup vs baseline: 1.6082x; 1.1686x over previous
//
#include <hip/hip_runtime.h>

#define N_NODES 50000
#define N_EDGES 800000
#define F 64   // IN_FEATS == HIDDEN
#define C 32   // NUM_CLASSES
#define NCOPY 8          // privatized histogram copies
#define CUR_STRIDE 16    // cursor padding: 1 int per 64B line

// ---------------- degree count: one thread per edge, 8-way privatized ----------------
__global__ void deg8_kernel(const int* __restrict__ src, const int* __restrict__ dst,
                            int* __restrict__ out8, int* __restrict__ in8) {
    int e = blockIdx.x * blockDim.x + threadIdx.x;
    int copy = blockIdx.x & (NCOPY - 1);
    if (e < N_EDGES) {
        atomicAdd(&out8[copy * N_NODES + src[e]], 1);
        atomicAdd(&in8[copy * N_NODES + dst[e]], 1);
    }
}

// sum 8 copies -> norms + compact in-count
__global__ void reduce_norm_kernel(const int* __restrict__ out8, const int* __restrict__ in8,
                                   float* __restrict__ norm_src, float* __restrict__ norm_dst,
                                   int* __restrict__ cnt) {
    int i = blockIdx.x * blockDim.x + threadIdx.x;
    if (i < N_NODES) {
        int so = 0, si = 0;
#pragma unroll
        for (int c = 0; c < NCOPY; c++) {
            so += out8[c * N_NODES + i];
            si += in8[c * N_NODES + i];
        }
        norm_src[i] = rsqrtf(fmaxf((float)so, 1.0f));
        norm_dst[i] = rsqrtf(fmaxf((float)si, 1.0f));
        cnt[i] = si;
    }
}

// ---------------- hierarchical exclusive scan of cnt[N] ----------------
__global__ void scan1_kernel(const int* __restrict__ cnt, int* __restrict__ bsum) {
    __shared__ int ws[4];
    int t = threadIdx.x, lane = t & 63, w = t >> 6;
    int i = blockIdx.x * 256 + t;
    int v = (i < N_NODES) ? cnt[i] : 0;
#pragma unroll
    for (int off = 32; off > 0; off >>= 1) v += __shfl_down(v, off);
    if (lane == 0) ws[w] = v;
    __syncthreads();
    if (t == 0) bsum[blockIdx.x] = ws[0] + ws[1] + ws[2] + ws[3];
}

__global__ void scan2_kernel(const int* __restrict__ bsum, int* __restrict__ boff,
                             int* __restrict__ row_start, int nblocks) {
    __shared__ int wsum[4];
    int t = threadIdx.x, lane = t & 63, w = t >> 6;
    int v = (t < nblocks) ? bsum[t] : 0;
    int incl = v;
#pragma unroll
    for (int off = 1; off < 64; off <<= 1) {
        int u = __shfl_up(incl, off);
        if (lane >= off) incl += u;
    }
    if (lane == 63) wsum[w] = incl;
    __syncthreads();
    int wo = 0;
    for (int c = 0; c < w; c++) wo += wsum[c];
    if (t < nblocks) boff[t] = wo + incl - v;
    if (t == 255) row_start[N_NODES] = wo + incl;   // total == N_EDGES
}

__global__ void scan3_kernel(const int* __restrict__ cnt, const int* __restrict__ boff,
                             int* __restrict__ row_start, int* __restrict__ cursor) {
    __shared__ int wsum[4];
    int t = threadIdx.x, lane = t & 63, w = t >> 6;
    int i = blockIdx.x * 256 + t;
    int v = (i < N_NODES) ? cnt[i] : 0;
    int incl = v;
#pragma unroll
    for (int off = 1; off < 64; off <<= 1) {
        int u = __shfl_up(incl, off);
        if (lane >= off) incl += u;
    }
    if (lane == 63) wsum[w] = incl;
    __syncthreads();
    int wo = 0;
    for (int c = 0; c < w; c++) wo += wsum[c];
    if (i < N_NODES) {
        int excl = boff[blockIdx.x] + wo + incl - v;
        row_start[i] = excl;
        cursor[(size_t)i * CUR_STRIDE] = excl;
    }
}

// ---------------- CSR build: atomic-ticket placement (padded cursor) ----------------
__global__ void csr_kernel(const int* __restrict__ src, const int* __restrict__ dst,
                           int* __restrict__ cursor, int* __restrict__ csr) {
    int e = blockIdx.x * blockDim.x + threadIdx.x;
    if (e < N_EDGES) {
        int pos = atomicAdd(&cursor[(size_t)dst[e] * CUR_STRIDE], 1);
        csr[pos] = src[e];
    }
}

// ---------------- y = (x @ W1) * norm_src  [N x 64] ----------------
__global__ void gemm_y_kernel(const float* __restrict__ x,
                              const float* __restrict__ norm_src,
                              const float* __restrict__ W,   // [F][F]
                              float* __restrict__ y) {
    __shared__ float sW[F * F];
    __shared__ float srow[4][F];
    int t = threadIdx.x;
    for (int i = t; i < F * F; i += 256) sW[i] = W[i];
    int local = t >> 6;
    int j     = t & 63;
    int node  = blockIdx.x * 4 + local;
    float ns = 0.0f;
    if (node < N_NODES) {
        srow[local][j] = x[(size_t)node * F + j];
        ns = norm_src[node];
    }
    __syncthreads();
    if (node < N_NODES) {
        float acc = 0.0f;
#pragma unroll
        for (int i = 0; i < F; i++) acc += srow[local][i] * sW[i * F + j];
        y[(size_t)node * F + j] = acc * ns;
    }
}

// ---------------- gather64 + fused epilogue: h1 = relu(sum*nd + b1) ----------------
__global__ void gather64_kernel(const float* __restrict__ y,
                                const int* __restrict__ csr,
                                const int* __restrict__ row_start,
                                const float* __restrict__ norm_dst,
                                const float* __restrict__ b1,
                                float* __restrict__ h1) {
    int gid  = blockIdx.x * blockDim.x + threadIdx.x;
    int node = gid >> 6;
    int lane = threadIdx.x & 63;
    if (node >= N_NODES) return;
    int s0 = row_start[node], s1 = row_start[node + 1];
    float acc = 0.0f;
    int e = s0;
    for (; e + 1 < s1; e += 2) {
        int sa = csr[e], sb = csr[e + 1];
        acc += y[(size_t)sa * F + lane];
        acc += y[(size_t)sb * F + lane];
    }
    if (e < s1) acc += y[(size_t)csr[e] * F + lane];
    h1[(size_t)node * F + lane] = fmaxf(acc * norm_dst[node] + b1[lane], 0.0f);
}

// ---------------- g = (h1 @ W2) * norm_src  [N x 32] ----------------
__global__ void gemm_g_kernel(const float* __restrict__ h1,
                              const float* __restrict__ norm_src,
                              const float* __restrict__ W,   // [F][C]
                              float* __restrict__ g) {
    __shared__ float sW[F * C];
    __shared__ float srow[8][F];
    int t = threadIdx.x;
    for (int i = t; i < F * C; i += 256) sW[i] = W[i];
    int local = t >> 5;
    int j     = t & 31;
    int node  = blockIdx.x * 8 + local;
    float ns = 0.0f;
    if (node < N_NODES) {
        srow[local][j]      = h1[(size_t)node * F + j];
        srow[local][j + 32] = h1[(size_t)node * F + j + 32];
        ns = norm_src[node];
    }
    __syncthreads();
    if (node < N_NODES) {
        float acc = 0.0f;
#pragma unroll
        for (int i = 0; i < F; i++) acc += srow[local][i] * sW[i * C + j];
        g[(size_t)node * C + j] = acc * ns;
    }
}

// ---------------- gather32 + epilogue ----------------
__global__ void gather32_kernel(const float* __restrict__ g,
                                const int* __restrict__ csr,
                                const int* __restrict__ row_start,
                                const float* __restrict__ norm_dst,
                                const float* __restrict__ b2,
                                float* __restrict__ out) {
    int gid  = blockIdx.x * blockDim.x + threadIdx.x;
    int node = gid >> 6;
    if (node >= N_NODES) return;
    int lane = threadIdx.x & 63;
    int feat = lane & 31;
    int half = lane >> 5;
    int s0 = row_start[node], s1 = row_start[node + 1];
    float acc = 0.0f;
    for (int e = s0 + half; e < s1; e += 2) {
        acc += g[(size_t)csr[e] * C + feat];
    }
    acc += __shfl_down(acc, 32);
    if (half == 0) out[(size_t)node * C + feat] = acc * norm_dst[node] + b2[feat];
}

extern "C" void kernel_launch(void* const* d_in, const int* in_sizes, int n_in,
                              void* d_out, int out_size, void* d_ws, size_t ws_size,
                              hipStream_t stream) {
    const float* features = (const float*)d_in[0];   // [N, 64]
    const int*   src      = (const int*)d_in[1];     // [E]
    const int*   dst      = (const int*)d_in[2];     // [E]
    const float* W1       = (const float*)d_in[3];   // [64,64]
    const float* b1       = (const float*)d_in[4];   // [64]
    const float* W2       = (const float*)d_in[5];   // [64,32]
    const float* b2       = (const float*)d_in[6];   // [32]
    float* out = (float*)d_out;                      // [N, 32]

    const int NB = (N_NODES + 255) / 256;            // 196

    // ---- workspace layout: EXACTLY R2's proven 29.6 MB footprint ----
    //   norm_src[N] | norm_dst[N] | cnt[N] | row_start[N+1] | csr[E] | y[N*F] | h1[N*F]
    // All transient build buffers (out8/in8/cursor/bsum/boff) ALIAS the y region:
    // they are dead before gemm_y writes y (stream-ordered dispatches).
    char* p = (char*)d_ws;
    float* norm_src  = (float*)p;            p += (size_t)N_NODES * 4;
    float* norm_dst  = (float*)p;            p += (size_t)N_NODES * 4;
    int*   cnt       = (int*)p;              p += (size_t)N_NODES * 4;
    int*   row_start = (int*)p;              p += (size_t)(N_NODES + 1) * 4;
    int*   csr       = (int*)p;              p += (size_t)N_EDGES * 4;            // 3.2 MB
    float* y         = (float*)p;            p += (size_t)N_NODES * F * 4;        // 12.8 MB
    float* h1        = (float*)p;            /* 12.8 MB */
    float* g         = y;   // layer-2 reuse

    // aliases inside the 12.8 MB y region (mutually disjoint):
    int* out8   = (int*)y;                              // 8N ints = 1.6 MB
    int* in8    = out8 + NCOPY * N_NODES;               // 1.6 MB
    int* cursor = in8  + NCOPY * N_NODES;               // N*16 ints = 3.2 MB (ends at 6.4 MB)
    int* bsum   = cursor + (size_t)N_NODES * CUR_STRIDE; // 256 ints
    int* boff   = bsum + 256;                            // 256 ints

    // 1) degrees (privatized histograms)
    hipMemsetAsync(out8, 0, (size_t)2 * NCOPY * N_NODES * 4, stream);
    deg8_kernel<<<(N_EDGES + 255) / 256, 256, 0, stream>>>(src, dst, out8, in8);
    reduce_norm_kernel<<<NB, 256, 0, stream>>>(out8, in8, norm_src, norm_dst, cnt);

    // 2) scan -> row_start, cursor; CSR build
    scan1_kernel<<<NB, 256, 0, stream>>>(cnt, bsum);
    scan2_kernel<<<1, 256, 0, stream>>>(bsum, boff, row_start, NB);
    scan3_kernel<<<NB, 256, 0, stream>>>(cnt, boff, row_start, cursor);
    csr_kernel<<<(N_EDGES + 255) / 256, 256, 0, stream>>>(src, dst, cursor, csr);

    // 3) layer 1  (gemm_y overwrites the alias region — all aliases dead by now)
    gemm_y_kernel<<<(N_NODES + 3) / 4, 256, 0, stream>>>(features, norm_src, W1, y);
    gather64_kernel<<<(N_NODES * 64) / 256, 256, 0, stream>>>(y, csr, row_start, norm_dst, b1, h1);

    // 4) layer 2
    gemm_g_kernel<<<(N_NODES + 7) / 8, 256, 0, stream>>>(h1, norm_src, W2, g);
    gather32_kernel<<<(N_NODES * 64) / 256, 256, 0, stream>>>(g, csr, row_start, norm_dst, b2, out);
}